// Round 1
// baseline (71.875 us; speedup 1.0000x reference)
//
#include <hip/hip_runtime.h>

#define S 14
#define NBATCH 4096
#define TOTAL (NBATCH * S * S)

constexpr float STEP_C       = 1.0f / 14.0f;
constexpr float EPS_C        = 1e-6f;
constexpr float LAMBDA_NOOBJ = 0.2f;
constexpr float LAMBDA_COORD = 7.0f;
constexpr float LAMBDA_CLS   = 1.5f;
constexpr float INV_N        = 1.0f / (float)NBATCH;
constexpr float C_V          = 0.40528473456935109f; // 4/pi^2

struct Box { float x0, y0, x1, y1; };

__device__ inline float iou_fn(const Box& a, const Box& b) {
    float x1 = fmaxf(a.x0, b.x0), y1 = fmaxf(a.y0, b.y0);
    float x2 = fminf(a.x1, b.x1), y2 = fminf(a.y1, b.y1);
    float inter = fmaxf(x2 - x1, 0.0f) * fmaxf(y2 - y1, 0.0f);
    float area1 = (a.x1 - a.x0) * (a.y1 - a.y0);
    float area2 = (b.x1 - b.x0) * (b.y1 - b.y0);
    return inter / (area1 + area2 - inter + EPS_C);
}

__device__ inline float ciou_loss(const Box& a, const Box& b, float iou) {
    float cx1 = (a.x0 + a.x1) * 0.5f, cy1 = (a.y0 + a.y1) * 0.5f;
    float cx2 = (b.x0 + b.x1) * 0.5f, cy2 = (b.y0 + b.y1) * 0.5f;
    float cd = (cx1 - cx2) * (cx1 - cx2) + (cy1 - cy2) * (cy1 - cy2);
    float xc1 = fminf(a.x0, b.x0), yc1 = fminf(a.y0, b.y0);
    float xc2 = fmaxf(a.x1, b.x1), yc2 = fmaxf(a.y1, b.y1);
    float od = (xc2 - xc1) * (xc2 - xc1) + (yc2 - yc1) * (yc2 - yc1) + EPS_C;
    float w1 = fmaxf(a.x1 - a.x0, EPS_C), h1 = fmaxf(a.y1 - a.y0, EPS_C);
    float w2 = fmaxf(b.x1 - b.x0, EPS_C), h2 = fmaxf(b.y1 - b.y0, EPS_C);
    float d = atanf(w2 / h2) - atanf(w1 / h1);
    float v = C_V * d * d;
    float alpha = v / (1.0f - iou + v + EPS_C);
    float ciou = iou - cd / od - alpha * v;
    float scale = fmaxf(2.0f - w2 * h2, 1.0f);
    return (1.0f - ciou) * scale;
}

__global__ __launch_bounds__(256) void yolo_loss_kernel(
    const float* __restrict__ pred, const float* __restrict__ target,
    float* __restrict__ out) {
    int cell = blockIdx.x * 256 + threadIdx.x;
    float contrib = 0.0f;
    if (cell < TOTAL) {
        int j = cell % S;             // gx axis (dim 2)
        int i = (cell / S) % S;       // gy axis (dim 1)
        float gx = (float)j, gy = (float)i;
        const float* p = pred   + (size_t)cell * 30;
        const float* t = target + (size_t)cell * 30;

        float pb[10], tb[10];
        #pragma unroll
        for (int k = 0; k < 10; ++k) { pb[k] = p[k]; tb[k] = t[k]; }

        bool obj0 = tb[4] > 0.0f;
        bool obj1 = tb[9] > 0.0f;
        bool sig  = obj1;

        Box b1[2], b2[2];
        float iou[2];
        #pragma unroll
        for (int b = 0; b < 2; ++b) {
            float px = (pb[b * 5 + 0] + gx) * STEP_C;
            float py = (pb[b * 5 + 1] + gy) * STEP_C;
            float pw = pb[b * 5 + 2], ph = pb[b * 5 + 3];
            b1[b] = { px - pw * 0.5f, py - ph * 0.5f, px + pw * 0.5f, py + ph * 0.5f };
            float tx = (tb[b * 5 + 0] + gx) * STEP_C;
            float ty = (tb[b * 5 + 1] + gy) * STEP_C;
            float tw = tb[b * 5 + 2], th = tb[b * 5 + 3];
            b2[b] = { tx - tw * 0.5f, ty - th * 0.5f, tx + tw * 0.5f, ty + th * 0.5f };
            iou[b] = iou_fn(b1[b], b2[b]);
        }

        // jnp.argmax: first max wins ties -> resp=1 only if strictly greater
        int resp = (iou[1] > iou[0]) ? 1 : 0;

        #pragma unroll
        for (int b = 0; b < 2; ++b) {
            bool obj      = (b == 0) ? obj0 : obj1;
            bool suppress = sig && (b == (1 - resp));
            bool obj_m    = obj && !suppress;
            float d  = pb[b * 5 + 4] - tb[b * 5 + 4];
            float dc = d * d;
            contrib += obj_m ? dc : (LAMBDA_NOOBJ * dc);
            if (sig && obj_m)
                contrib += LAMBDA_COORD * ciou_loss(b1[b], b2[b], iou[b]);
        }

        if (sig) {
            float bce = 0.0f;
            #pragma unroll
            for (int c = 0; c < 20; ++c) {
                float pc = p[10 + c];
                float tc = t[10 + c];
                pc = fminf(fmaxf(pc, 1e-7f), 1.0f - 1e-7f);
                bce += -(tc * logf(pc) + (1.0f - tc) * log1pf(-pc));
            }
            contrib += LAMBDA_CLS * bce;
        }
    }

    // wave-64 reduce, then cross-wave via LDS, one atomic per block
    float v = contrib;
    #pragma unroll
    for (int off = 32; off > 0; off >>= 1) v += __shfl_down(v, off);

    __shared__ float ws[4];
    int lane = threadIdx.x & 63;
    int wid  = threadIdx.x >> 6;
    if (lane == 0) ws[wid] = v;
    __syncthreads();
    if (threadIdx.x == 0) {
        float s = ws[0] + ws[1] + ws[2] + ws[3];
        atomicAdd(out, s * INV_N);
    }
}

extern "C" void kernel_launch(void* const* d_in, const int* in_sizes, int n_in,
                              void* d_out, int out_size, void* d_ws, size_t ws_size,
                              hipStream_t stream) {
    const float* pred   = (const float*)d_in[0];
    const float* target = (const float*)d_in[1];
    float* out = (float*)d_out;

    hipMemsetAsync(d_out, 0, sizeof(float), stream);

    int blocks = (TOTAL + 255) / 256;
    hipLaunchKernelGGL(yolo_loss_kernel, dim3(blocks), dim3(256), 0, stream,
                       pred, target, out);
}